// Round 1
// baseline (2818.152 us; speedup 1.0000x reference)
//
#include <hip/hip_runtime.h>
#include <math.h>

// Problem constants (match reference)
#define NROWS   200000
#define HIDDEN  512
#define NCOL    256     // HID/2
#define NGRAPH  2000

// Tiling
#define BM      64      // rows per block
#define KC      32      // K chunk
#define HPAD    36      // KC + 4 pad (bank spread, keeps 16B alignment)
#define WPAD    36

__global__ void zero_out_kernel(float* __restrict__ out, int n) {
    int i = blockIdx.x * blockDim.x + threadIdx.x;
    if (i < n) out[i] = 0.0f;
}

// Fused: y = h@W1.T + b1 ; x2 = silu(y)@W2.T + b2 ; alpha = h@Ww.T + bw
//        x = x2*alpha ; out = segment_sum(x, batch)
// Block: 256 threads = 8 row-groups x 32 col-groups.
// Thread (r,c): rows r*8..r*8+7 (local), cols {c + 32*j}, acc[8][8] in regs.
__global__ __launch_bounds__(256, 2)
void fused_kernel(const float* __restrict__ h,
                  const int*   __restrict__ batch,
                  const float* __restrict__ W1,
                  const float* __restrict__ b1,
                  const float* __restrict__ W2,
                  const float* __restrict__ b2,
                  const float* __restrict__ Ww,
                  const float* __restrict__ bw,
                  float* __restrict__ out) {
    __shared__ float h_t[BM][HPAD];     // h_t[row][k]
    __shared__ float w_t[NCOL][WPAD];   // w_t[col][k]
    __shared__ float xrow[BM];

    const int t = threadIdx.x;
    const int r = t >> 5;     // 0..7
    const int c = t & 31;     // 0..31
    const long row0 = (long)blockIdx.x * BM;

    float acc[8][8];
    float aacc[8];
#pragma unroll
    for (int i = 0; i < 8; ++i) {
        aacc[i] = 0.0f;
#pragma unroll
        for (int j = 0; j < 8; ++j) acc[i][j] = 0.0f;
    }

    for (int kk = 0; kk < HIDDEN; kk += KC) {
        __syncthreads();   // previous chunk's reads done before overwrite
        // stage h tile: 64 rows x 32 k  (512 float4, 2 per thread)
#pragma unroll
        for (int p = 0; p < 2; ++p) {
            int idx = p * 256 + t;
            int rr  = idx >> 3;          // 8 float4 per row
            int f4  = idx & 7;
            const float4 v = *reinterpret_cast<const float4*>(
                h + (row0 + rr) * HIDDEN + kk + f4 * 4);
            *reinterpret_cast<float4*>(&h_t[rr][f4 * 4]) = v;
        }
        // stage W1 tile: 256 cols x 32 k (2048 float4, 8 per thread)
#pragma unroll
        for (int p = 0; p < 8; ++p) {
            int idx = p * 256 + t;
            int cc  = idx >> 3;
            int f4  = idx & 7;
            const float4 v = *reinterpret_cast<const float4*>(
                W1 + (long)cc * HIDDEN + kk + f4 * 4);
            *reinterpret_cast<float4*>(&w_t[cc][f4 * 4]) = v;
        }
        __syncthreads();

        // alpha partial: this thread covers global k = kk + c for its 8 rows
        {
            const float wwk = Ww[kk + c];
#pragma unroll
            for (int i = 0; i < 8; ++i)
                aacc[i] += h_t[r * 8 + i][c] * wwk;
        }

        // main GEMM: 8 k-quads per chunk
#pragma unroll
        for (int q = 0; q < KC / 4; ++q) {
            float4 hv[8];
#pragma unroll
            for (int i = 0; i < 8; ++i)
                hv[i] = *reinterpret_cast<const float4*>(&h_t[r * 8 + i][q * 4]);
#pragma unroll
            for (int j = 0; j < 8; ++j) {
                const float4 wv =
                    *reinterpret_cast<const float4*>(&w_t[c + 32 * j][q * 4]);
#pragma unroll
                for (int i = 0; i < 8; ++i) {
                    acc[i][j] += hv[i].x * wv.x;
                    acc[i][j] += hv[i].y * wv.y;
                    acc[i][j] += hv[i].z * wv.z;
                    acc[i][j] += hv[i].w * wv.w;
                }
            }
        }
    }

    // epilogue: bias + silu + W2 partial dot over this thread's 8 cols
    float x2p[8];
#pragma unroll
    for (int i = 0; i < 8; ++i) x2p[i] = 0.0f;
#pragma unroll
    for (int j = 0; j < 8; ++j) {
        const int col = c + 32 * j;
        const float b1v = b1[col];
        const float w2v = W2[col];
#pragma unroll
        for (int i = 0; i < 8; ++i) {
            const float y = acc[i][j] + b1v;
            const float s = y / (1.0f + __expf(-y));   // silu
            x2p[i] += s * w2v;
        }
    }
    // reduce across the 32 col-groups (half-wave butterflies; c = lane&31)
#pragma unroll
    for (int off = 1; off < 32; off <<= 1) {
#pragma unroll
        for (int i = 0; i < 8; ++i) {
            x2p[i]  += __shfl_xor(x2p[i], off);
            aacc[i] += __shfl_xor(aacc[i], off);
        }
    }
    if (c == 0) {
        const float b2v = b2[0];
        const float bwv = bw[0];
#pragma unroll
        for (int i = 0; i < 8; ++i) {
            const float x2 = x2p[i] + b2v;
            const float al = aacc[i] + bwv;
            xrow[r * 8 + i] = x2 * al;
        }
    }
    __syncthreads();

    // segment-sum staging: wave 0 does a 64-lane segmented inclusive scan
    // (batch is globally sorted), then one atomic per run tail.
    if (t < 64) {
        const int b = batch[row0 + t];
        float v = xrow[t];
#pragma unroll
        for (int off = 1; off < 64; off <<= 1) {
            const int   bp = __shfl_up(b, off);
            const float vp = __shfl_up(v, off);
            if (t >= off && bp == b) v += vp;
        }
        const int bn = __shfl_down(b, 1);
        if (t == 63 || bn != b) atomicAdd(&out[b], v);
    }
}

extern "C" void kernel_launch(void* const* d_in, const int* in_sizes, int n_in,
                              void* d_out, int out_size, void* d_ws, size_t ws_size,
                              hipStream_t stream) {
    const float* h     = (const float*)d_in[0];
    // d_in[1] edge_index, d_in[2] edge_weight, d_in[4] alpha: unused by reference
    const int*   batch = (const int*)d_in[3];
    const float* W1    = (const float*)d_in[5];
    const float* b1    = (const float*)d_in[6];
    const float* W2    = (const float*)d_in[7];
    const float* b2    = (const float*)d_in[8];
    const float* Ww    = (const float*)d_in[9];
    const float* bw    = (const float*)d_in[10];
    float* out = (float*)d_out;

    zero_out_kernel<<<(NGRAPH + 255) / 256, 256, 0, stream>>>(out, NGRAPH);

    const int nblocks = NROWS / BM;   // 3125, exact
    fused_kernel<<<nblocks, 256, 0, stream>>>(h, batch, W1, b1, W2, b2, Ww, bw, out);
}

// Round 2
// 965.754 us; speedup vs baseline: 2.9181x; 2.9181x over previous
//
#include <hip/hip_runtime.h>

// Problem constants (match reference)
#define NROWS   200000
#define HIDDEN  512
#define NCOL    256     // HID/2
#define NGRAPH  2000

typedef __attribute__((ext_vector_type(8))) short bf16x8;   // 8 bf16 = 4 VGPRs
typedef __attribute__((ext_vector_type(4))) float f32x4;    // MFMA C/D

// f32 -> bf16 round-to-nearest-even (bit trick; inputs are finite randoms)
static __device__ __forceinline__ short f2bf(float f) {
    union { float f; unsigned u; } v; v.f = f;
    unsigned r = v.u + 0x7FFFu + ((v.u >> 16) & 1u);
    return (short)(r >> 16);
}

// One-shot prep: convert W1 (f32 [256][512]) to bf16 in d_ws, zero the output.
// (d_ws is re-poisoned 0xAA before every timed launch, so this runs every call.)
__global__ void prep_kernel(const float* __restrict__ w1,
                            short* __restrict__ w1bf,
                            float* __restrict__ out) {
    int i = blockIdx.x * blockDim.x + threadIdx.x;
    if (i < NCOL * HIDDEN) w1bf[i] = f2bf(w1[i]);
    if (i < NGRAPH) out[i] = 0.0f;
}

// Fused: y = h@W1.T + b1 ; x2 = silu(y)@W2.T + b2 ; alpha = h@Ww.T + bw
//        x = x2*alpha ; out = segment_sum(x, batch)
//
// Block = 256 threads = 4 waves. Wave w owns 16 rows (one 16-row M-tile),
// full N=256 (16 col-tiles), K looped in steps of 32 via mfma_f32_16x16x32_bf16.
// A-frag: lane l holds h[row0 + (l&15)][k0 + 8*(l>>4) .. +7] (16B contiguous).
// B-frag: lane l holds W1bf[n = 16j + (l&15)][k0 + 8*(l>>4) .. +7].
// C/D:    lane l, reg q -> row = 4*(l>>4)+q, col = (l&15)   [m89-verified map]
// No LDS tiles, no main-loop barriers; B is L2/L1-resident (256 KB).
__global__ __launch_bounds__(256)
void fused_mfma(const float* __restrict__ h,
                const int*   __restrict__ batch,
                const short* __restrict__ w1bf,
                const float* __restrict__ b1,
                const float* __restrict__ W2,
                const float* __restrict__ b2,
                const float* __restrict__ Ww,
                const float* __restrict__ bw,
                float* __restrict__ out) {
    __shared__ float xr[64];   // per-row x2 partial (pre-bias)
    __shared__ float al[64];   // per-row alpha partial (pre-bias)

    const int t   = threadIdx.x;
    const int wid = t >> 6;    // wave 0..3
    const int l   = t & 63;
    const int lo  = l & 15;    // A row / B col / D col within tile
    const int hi  = l >> 4;    // k-slice 0..3
    const long rowblk = (long)blockIdx.x * 64;
    const long arow   = rowblk + wid * 16 + lo;

    f32x4 acc[16];
#pragma unroll
    for (int j = 0; j < 16; ++j) acc[j] = (f32x4){0.f, 0.f, 0.f, 0.f};
    float ap = 0.f;   // alpha partial for row `arow`, k-slice `hi`

    const float* hp = h    + arow * HIDDEN + hi * 8;
    const float* wp = Ww   + hi * 8;
    const short* bp = w1bf + lo * HIDDEN + hi * 8;

    for (int ks = 0; ks < HIDDEN / 32; ++ks) {
        const float4 a0 = *(const float4*)(hp);
        const float4 a1 = *(const float4*)(hp + 4);
        // alpha from the f32 values (h read exactly once from HBM)
        const float4 w0 = *(const float4*)(wp);
        const float4 w1v = *(const float4*)(wp + 4);
        ap += a0.x * w0.x + a0.y * w0.y + a0.z * w0.z + a0.w * w0.w
            + a1.x * w1v.x + a1.y * w1v.y + a1.z * w1v.z + a1.w * w1v.w;

        bf16x8 af;
        af[0] = f2bf(a0.x); af[1] = f2bf(a0.y); af[2] = f2bf(a0.z); af[3] = f2bf(a0.w);
        af[4] = f2bf(a1.x); af[5] = f2bf(a1.y); af[6] = f2bf(a1.z); af[7] = f2bf(a1.w);

#pragma unroll
        for (int j = 0; j < 16; ++j) {
            const bf16x8 bf = *(const bf16x8*)(bp + j * 16 * HIDDEN);
            acc[j] = __builtin_amdgcn_mfma_f32_16x16x32_bf16(af, bf, acc[j], 0, 0, 0);
        }
        hp += 32; wp += 32; bp += 32;
    }

    // Epilogue: bias + silu + W2 dot (per-lane over its 16 cols x 4 rows)
    float xp[4] = {0.f, 0.f, 0.f, 0.f};
#pragma unroll
    for (int j = 0; j < 16; ++j) {
        const int col = j * 16 + lo;
        const float b1v = b1[col];
        const float w2v = W2[col];
#pragma unroll
        for (int q = 0; q < 4; ++q) {
            const float y = acc[j][q] + b1v;
            const float s = y / (1.0f + __expf(-y));   // silu
            xp[q] += s * w2v;
        }
    }
    // reduce x2 over the 16 col-lanes (low 4 lane bits)
#pragma unroll
    for (int m = 1; m < 16; m <<= 1) {
#pragma unroll
        for (int q = 0; q < 4; ++q) xp[q] += __shfl_xor(xp[q], m);
    }
    // reduce alpha over the 4 k-slices (lane bits 4..5)
    ap += __shfl_xor(ap, 16);
    ap += __shfl_xor(ap, 32);

    if (lo == 0) {   // lanes 0,16,32,48 -> rows hi*4+q of this wave
#pragma unroll
        for (int q = 0; q < 4; ++q) xr[wid * 16 + hi * 4 + q] = xp[q];
    }
    if (l < 16) al[wid * 16 + l] = ap;
    __syncthreads();

    // 64-lane segmented inclusive scan over sorted batch, atomic per run tail
    // (verified in round 1: absmax 0.0)
    if (t < 64) {
        const int b = batch[rowblk + t];
        float v = (xr[t] + b2[0]) * (al[t] + bw[0]);
#pragma unroll
        for (int off = 1; off < 64; off <<= 1) {
            const int   bpv = __shfl_up(b, off);
            const float vp  = __shfl_up(v, off);
            if (t >= off && bpv == b) v += vp;
        }
        const int bn = __shfl_down(b, 1);
        if (t == 63 || bn != b) atomicAdd(&out[b], v);
    }
}

extern "C" void kernel_launch(void* const* d_in, const int* in_sizes, int n_in,
                              void* d_out, int out_size, void* d_ws, size_t ws_size,
                              hipStream_t stream) {
    const float* h     = (const float*)d_in[0];
    // d_in[1] edge_index, d_in[2] edge_weight, d_in[4] alpha: unused by reference
    const int*   batch = (const int*)d_in[3];
    const float* W1    = (const float*)d_in[5];
    const float* b1    = (const float*)d_in[6];
    const float* W2    = (const float*)d_in[7];
    const float* b2    = (const float*)d_in[8];
    const float* Ww    = (const float*)d_in[9];
    const float* bw    = (const float*)d_in[10];
    float* out  = (float*)d_out;
    short* w1bf = (short*)d_ws;          // 256 KB of workspace

    // prep: 512*256 = 131072 threads covers W1 (131072 elems) and out (2000)
    prep_kernel<<<512, 256, 0, stream>>>(W1, w1bf, out);

    fused_mfma<<<NROWS / 64, 256, 0, stream>>>(h, batch, w1bf,
                                               b1, W2, b2, Ww, bw, out);
}